// Round 23
// baseline (250.166 us; speedup 1.0000x reference)
//
#include <hip/hip_runtime.h>
#include <hip/hip_bf16.h>

typedef __attribute__((ext_vector_type(8))) short short8;   // 8 bf16 (4 VGPRs)
typedef __attribute__((ext_vector_type(4))) float f32x4;    // MFMA 16x16 C/D

#define NB 8
#define NC 256
#define NN 4096
#define ND 32
#define LOG2E 1.44269504088896340736f

static __device__ __forceinline__ ushort f2bf(float f) {
  __hip_bfloat16 h = __float2bfloat16(f);
  return reinterpret_cast<ushort&>(h);
}
static __device__ __forceinline__ float bf2f(ushort u) {
  const uint v = ((uint)u) << 16;
  return __builtin_bit_cast(float, v);
}

// ---------------------------------------------------------------------------
// Projection via MFMA — R16 VERBATIM (validated: fast, absmax 0.125).
// ---------------------------------------------------------------------------
#define LDW 264   // Ws row stride (ushorts)
#define LDX 40    // Xs row stride (ushorts)
#define LDO 136   // Os row stride (ushorts)

__global__ __launch_bounds__(256, 2)
void proj_kernel(const float* __restrict__ x,
                 const float* __restrict__ wq, const float* __restrict__ bq,
                 const float* __restrict__ wk, const float* __restrict__ bk,
                 const float* __restrict__ wv, const float* __restrict__ bv,
                 ushort* __restrict__ qk, ushort* __restrict__ vt) {
  __shared__ __align__(16) ushort Ws[2][64 * LDW];   // 67.6 KB
  __shared__ __align__(16) ushort Xs[128 * LDX];     // 10.2 KB

  const int n0 = blockIdx.x * 128;
  const int o0 = blockIdx.y * 64;
  const int b  = blockIdx.z;
  const int t  = threadIdx.x;
  const int w  = t >> 6;
  const int lane = t & 63;
  const int g16  = lane >> 4;
  const int c16  = lane & 15;

  {
    const int o  = t >> 2;
    const int cb = (t & 3) * 64;
    const int oa = o0 + o;
    const float* wrow;
    float scale = 1.0f;
    if (oa < 32)       { wrow = wq + (size_t)oa * NC; scale = LOG2E; }
    else if (oa < 64)  { wrow = wk + (size_t)(oa - 32) * NC; }
    else               { wrow = wv + (size_t)(oa - 64) * NC; }
#pragma unroll
    for (int cc = 0; cc < 64; cc += 8) {
      const float4 f0 = *(const float4*)(wrow + cb + cc);
      const float4 f1 = *(const float4*)(wrow + cb + cc + 4);
      float v[8] = {f0.x, f0.y, f0.z, f0.w, f1.x, f1.y, f1.z, f1.w};
      union { ushort u[8]; uint4 q; } hi, lo;
#pragma unroll
      for (int e = 0; e < 8; ++e) {
        const float s = v[e] * scale;
        const ushort h = f2bf(s);
        hi.u[e] = h;
        lo.u[e] = f2bf(s - bf2f(h));
      }
      *(uint4*)&Ws[0][o * LDW + cb + cc] = hi.q;
      *(uint4*)&Ws[1][o * LDW + cb + cc] = lo.q;
    }
  }

  f32x4 acc[8];
#pragma unroll
  for (int nt = 0; nt < 8; ++nt)
#pragma unroll
    for (int r = 0; r < 4; ++r) acc[nt][r] = 0.f;

  const int s_cc = w * 8 + (lane >> 3);
  const int s_nb = (lane & 7) * 4;

  for (int c0 = 0; c0 < NC; c0 += 32) {
    __syncthreads();
    {
      const float* xsrc = x + ((size_t)(b * NC + c0 + s_cc)) * NN + n0 + s_nb;
#pragma unroll
      for (int it = 0; it < 4; ++it) {
        const float4 f = *(const float4*)(xsrc + it * 32);
        const int n = s_nb + it * 32;
        Xs[(n + 0) * LDX + s_cc] = f2bf(f.x);
        Xs[(n + 1) * LDX + s_cc] = f2bf(f.y);
        Xs[(n + 2) * LDX + s_cc] = f2bf(f.z);
        Xs[(n + 3) * LDX + s_cc] = f2bf(f.w);
      }
    }
    __syncthreads();

    const short8 ah = *(const short8*)&Ws[0][(w * 16 + c16) * LDW + c0 + g16 * 8];
    const short8 al = *(const short8*)&Ws[1][(w * 16 + c16) * LDW + c0 + g16 * 8];
#pragma unroll
    for (int nt = 0; nt < 8; ++nt) {
      const short8 bf = *(const short8*)&Xs[(nt * 16 + c16) * LDX + g16 * 8];
      acc[nt] = __builtin_amdgcn_mfma_f32_16x16x32_bf16(ah, bf, acc[nt], 0, 0, 0);
      acc[nt] = __builtin_amdgcn_mfma_f32_16x16x32_bf16(al, bf, acc[nt], 0, 0, 0);
    }
  }

  if (blockIdx.y == 0) {
    float bb[4];
#pragma unroll
    for (int r = 0; r < 4; ++r) {
      const int o = w * 16 + g16 * 4 + r;
      bb[r] = (o < 32) ? bq[o] * LOG2E : bk[o - 32];
    }
#pragma unroll
    for (int nt = 0; nt < 8; ++nt) {
      union { ushort u[4]; uint2 v; } pk;
#pragma unroll
      for (int r = 0; r < 4; ++r) pk.u[r] = f2bf(acc[nt][r] + bb[r]);
      const int n = n0 + nt * 16 + c16;
      *(uint2*)(qk + ((size_t)(b * NN + n)) * 64 + w * 16 + g16 * 4) = pk.v;
    }
  } else {
    const int ch0 = o0 - 64;
    float bb[4];
#pragma unroll
    for (int r = 0; r < 4; ++r) bb[r] = bv[ch0 + w * 16 + g16 * 4 + r];
    __syncthreads();
    ushort* Os = &Ws[0][0];
#pragma unroll
    for (int nt = 0; nt < 8; ++nt) {
#pragma unroll
      for (int r = 0; r < 4; ++r)
        Os[(w * 16 + g16 * 4 + r) * LDO + nt * 16 + c16] =
            f2bf(acc[nt][r] + bb[r]);
    }
    __syncthreads();
    const int chl = t >> 2;
    const int nb  = (t & 3) * 32;
    ushort* dst = vt + ((size_t)(b * NC + ch0 + chl)) * NN + n0 + nb;
#pragma unroll
    for (int k = 0; k < 4; ++k)
      *(uint4*)(dst + k * 8) = *(const uint4*)&Os[chl * LDO + nb + k * 8];
  }
}

// ---------------------------------------------------------------------------
// Flash attention, BARRIER-FREE per-wave design.
// 512 blocks x 256 thr (4 waves). Block = (b, 64 q-rows); wave w = 64-channel
// group. Each wave INDEPENDENTLY: per 64-j chunk, computes S for its 64 rows
// (swapped mfma16(K,Q), exp2 with pre-scaled Q, f2bf pack, b64 writes into a
// WAVE-PRIVATE swizzled LDS tile P[64][64]) then PV (A=P from private LDS,
// B=V from global, 32 mfma16 into 64-AGPR acc). Same-wave LDS RAW is ordered
// by compiler lgkmcnt — NO __syncthreads anywhere: waves drift freely, so
// within-wave stalls are covered by the co-resident wave instead of being
// paid by a lockstepped block. Next-chunk K prefetched (kfn, +16 regs, cap
// 256 at launch_bounds(256,2)).
// Cost accepted: S duplicated x4 (MFMA total 103 GF -> 50 us chip floor);
// V read per-wave (1 GB L2 ~ 29 us, overlapped).
// PX swizzle: write & read use the same bijection -> layout-correct by
// construction; swizzle spreads the 128B-row-stride bank hotspot.
// ---------------------------------------------------------------------------
#define PX(r, c) (((r) << 6) + ((((c) & 56) ^ (((r) & 7) << 3)) | ((c) & 7)))

__global__ __launch_bounds__(256, 2)
void attn_kernel(const ushort* __restrict__ qk, const ushort* __restrict__ vt,
                 const float* __restrict__ x, const float* __restrict__ gamma,
                 float* __restrict__ out) {
  __shared__ __align__(16) ushort Pw[4][64 * 64];   // 32 KB, wave-private tiles
  __shared__ __align__(16) float lw[4][64];

  const int lin  = blockIdx.x;
  const int b    = lin & 7;              // XCD swizzle: batch per XCD L2
  const int i0   = (lin >> 3) * 64;      // this block's 64 q-rows
  const int t    = threadIdx.x;
  const int w    = t >> 6;               // 0..3 : channel group
  const int lane = t & 63;
  const int g16  = lane >> 4;
  const int c16  = lane & 15;
  const int ch0  = w * 64;

  const f32x4 zero = {0.f, 0.f, 0.f, 0.f};
  ushort* Pp = &Pw[w][0];

  // Q fragments (B-operand of swapped S): lane c16 = q-row within 16-group
  short8 qf[4];
#pragma unroll
  for (int ig = 0; ig < 4; ++ig)
    qf[ig] = *(const short8*)(
        qk + ((size_t)(b * NN + i0 + ig * 16 + c16)) * 64 + g16 * 8);

  const ushort* kbase = qk + ((size_t)b * NN) * 64 + 32 + g16 * 8;
  // V fragment bases: lane c16 = channel within 16-group, g16*8 = j offset
  const ushort* vb[4];
#pragma unroll
  for (int cf = 0; cf < 4; ++cf)
    vb[cf] = vt + ((size_t)(b * NC + ch0 + cf * 16 + c16)) * NN + g16 * 8;

  f32x4 o[4][4];   // [ig: 16-row group][cf: 16-ch group] = 64 AGPR
#pragma unroll
  for (int ig = 0; ig < 4; ++ig)
#pragma unroll
    for (int cf = 0; cf < 4; ++cf)
#pragma unroll
      for (int r = 0; r < 4; ++r) o[ig][cf][r] = 0.f;

  float lp[4] = {0.f, 0.f, 0.f, 0.f};   // row-sum partials (lane c16 = row)

  short8 kf[4], kfn[4];
#pragma unroll
  for (int kt = 0; kt < 4; ++kt)   // prologue: chunk 0 K
    kf[kt] = *(const short8*)(kbase + (size_t)(kt * 16 + c16) * 64);

  for (int jc = 0; jc < NN / 64; ++jc) {
    const int j0 = jc * 64;

    // ---- S: 16 mfma16, 64 exp2, 16 b64 writes into private P ----
#pragma unroll
    for (int ig = 0; ig < 4; ++ig) {
#pragma unroll
      for (int kt = 0; kt < 4; ++kt) {
        const f32x4 d = __builtin_amdgcn_mfma_f32_16x16x32_bf16(
            kf[kt], qf[ig], zero, 0, 0, 0);
        union { ushort u[4]; uint2 v; } pk;
#pragma unroll
        for (int r = 0; r < 4; ++r) {
          const float e = exp2f(d[r]);   // Q pre-scaled by log2e
          lp[ig] += e;
          pk.u[r] = f2bf(e);
        }
        // D layout: lane holds P[j = kt*16 + 4*g16 + r][i = c16]
        *(uint2*)&Pp[PX(ig * 16 + c16, kt * 16 + g16 * 4)] = pk.v;
      }
    }

    // ---- next-chunk K prefetch (hidden under PV) ----
    if (jc + 1 < NN / 64) {
#pragma unroll
      for (int kt = 0; kt < 4; ++kt)
        kfn[kt] = *(const short8*)(
            kbase + (size_t)(j0 + 64 + kt * 16 + c16) * 64);
    }

    // ---- PV: 2 K-steps x (4 P-reads + 4 V-loads + 16 mfma16) ----
#pragma unroll
    for (int ks = 0; ks < 2; ++ks) {
      short8 vf[4];
#pragma unroll
      for (int cf = 0; cf < 4; ++cf)
        vf[cf] = *(const short8*)(vb[cf] + j0 + ks * 32);
      short8 pa[4];
#pragma unroll
      for (int ig = 0; ig < 4; ++ig)
        pa[ig] = *(const short8*)&Pp[PX(ig * 16 + c16, ks * 32 + g16 * 8)];
#pragma unroll
      for (int ig = 0; ig < 4; ++ig)
#pragma unroll
        for (int cf = 0; cf < 4; ++cf)
          o[ig][cf] = __builtin_amdgcn_mfma_f32_16x16x32_bf16(
              pa[ig], vf[cf], o[ig][cf], 0, 0, 0);
    }

#pragma unroll
    for (int kt = 0; kt < 4; ++kt) kf[kt] = kfn[kt];
  }

  // ---- finalize row sums: reduce over the 4 g16 lane-groups ----
#pragma unroll
  for (int ig = 0; ig < 4; ++ig) {
    lp[ig] += __shfl_xor(lp[ig], 16);
    lp[ig] += __shfl_xor(lp[ig], 32);
  }
  if (g16 == 0) {
#pragma unroll
    for (int ig = 0; ig < 4; ++ig) lw[w][ig * 16 + c16] = lp[ig];
  }
  // wave-private LDS: compiler lgkmcnt orders write->read; shfl made all
  // g16==0 lanes hold the totals. (No cross-wave sharing -> no barrier.)

  // ---- epilogue: out = gamma*O/l + x  (f32x4 stores along n) ----
  const float g = gamma[0];
#pragma unroll
  for (int ig = 0; ig < 4; ++ig) {
    const f32x4 li = *(const f32x4*)&lw[w][ig * 16 + g16 * 4];
    f32x4 gi;
#pragma unroll
    for (int r = 0; r < 4; ++r) gi[r] = g / li[r];
    const int irow = i0 + ig * 16 + g16 * 4;   // D row = 4*g16 + r
#pragma unroll
    for (int cf = 0; cf < 4; ++cf) {
      const int c = ch0 + cf * 16 + c16;       // D col = c16
      const size_t base = ((size_t)(b * NC + c)) * NN + irow;
      const f32x4 xv = *(const f32x4*)(x + base);
      f32x4 ov;
#pragma unroll
      for (int r = 0; r < 4; ++r) ov[r] = o[ig][cf][r] * gi[r] + xv[r];
      *(f32x4*)(out + base) = ov;
    }
  }
}

extern "C" void kernel_launch(void* const* d_in, const int* in_sizes, int n_in,
                              void* d_out, int out_size, void* d_ws, size_t ws_size,
                              hipStream_t stream) {
  const float* x  = (const float*)d_in[0];
  const float* wq = (const float*)d_in[1];
  const float* bq = (const float*)d_in[2];
  const float* wk = (const float*)d_in[3];
  const float* bk = (const float*)d_in[4];
  const float* wv = (const float*)d_in[5];
  const float* bv = (const float*)d_in[6];
  const float* gm = (const float*)d_in[7];
  float* outp = (float*)d_out;

  ushort* qkw = (ushort*)d_ws;                       // [B][N][64]  bf16, 4 MB
  ushort* vtw = qkw + (size_t)NB * NN * 64;          // [B][C][N]   bf16, 16 MB

  proj_kernel<<<dim3(NN / 128, 5, NB), 256, 0, stream>>>(
      x, wq, bq, wk, bk, wv, bv, qkw, vtw);
  attn_kernel<<<dim3((NN / 64) * NB), 256, 0, stream>>>(qkw, vtw, x, gm, outp);
}

// Round 24
// 149.661 us; speedup vs baseline: 1.6715x; 1.6715x over previous
//
#include <hip/hip_runtime.h>
#include <hip/hip_bf16.h>

typedef __attribute__((ext_vector_type(8))) short short8;   // 8 bf16 (4 VGPRs)
typedef __attribute__((ext_vector_type(4))) float f32x4;    // MFMA 16x16 C/D
typedef __attribute__((ext_vector_type(16))) float f32x16;  // MFMA 32x32 C/D

#define NB 8
#define NC 256
#define NN 4096
#define ND 32
#define NCH 16   // attn j-chunks of 256
#define LOG2E 1.44269504088896340736f

// attn P tile [2][128][256] ushort, 16B-slot XOR swizzle (validated R8/R10).
#define PIDX(row, col) (((row) << 8) + ((col) ^ (((row) & 15) << 3)))

static __device__ __forceinline__ ushort f2bf(float f) {
  __hip_bfloat16 h = __float2bfloat16(f);
  return reinterpret_cast<ushort&>(h);
}
static __device__ __forceinline__ float bf2f(ushort u) {
  const uint v = ((uint)u) << 16;
  return __builtin_bit_cast(float, v);
}

// ---------------------------------------------------------------------------
// Projection via MFMA — R16 VERBATIM (validated: fast, absmax 0.125).
// ---------------------------------------------------------------------------
#define LDW 264   // Ws row stride (ushorts)
#define LDX 40    // Xs row stride (ushorts)
#define LDO 136   // Os row stride (ushorts)

__global__ __launch_bounds__(256, 2)
void proj_kernel(const float* __restrict__ x,
                 const float* __restrict__ wq, const float* __restrict__ bq,
                 const float* __restrict__ wk, const float* __restrict__ bk,
                 const float* __restrict__ wv, const float* __restrict__ bv,
                 ushort* __restrict__ qk, ushort* __restrict__ vt) {
  __shared__ __align__(16) ushort Ws[2][64 * LDW];   // 67.6 KB
  __shared__ __align__(16) ushort Xs[128 * LDX];     // 10.2 KB

  const int n0 = blockIdx.x * 128;
  const int o0 = blockIdx.y * 64;
  const int b  = blockIdx.z;
  const int t  = threadIdx.x;
  const int w  = t >> 6;
  const int lane = t & 63;
  const int g16  = lane >> 4;
  const int c16  = lane & 15;

  {
    const int o  = t >> 2;
    const int cb = (t & 3) * 64;
    const int oa = o0 + o;
    const float* wrow;
    float scale = 1.0f;
    if (oa < 32)       { wrow = wq + (size_t)oa * NC; scale = LOG2E; }
    else if (oa < 64)  { wrow = wk + (size_t)(oa - 32) * NC; }
    else               { wrow = wv + (size_t)(oa - 64) * NC; }
#pragma unroll
    for (int cc = 0; cc < 64; cc += 8) {
      const float4 f0 = *(const float4*)(wrow + cb + cc);
      const float4 f1 = *(const float4*)(wrow + cb + cc + 4);
      float v[8] = {f0.x, f0.y, f0.z, f0.w, f1.x, f1.y, f1.z, f1.w};
      union { ushort u[8]; uint4 q; } hi, lo;
#pragma unroll
      for (int e = 0; e < 8; ++e) {
        const float s = v[e] * scale;
        const ushort h = f2bf(s);
        hi.u[e] = h;
        lo.u[e] = f2bf(s - bf2f(h));
      }
      *(uint4*)&Ws[0][o * LDW + cb + cc] = hi.q;
      *(uint4*)&Ws[1][o * LDW + cb + cc] = lo.q;
    }
  }

  f32x4 acc[8];
#pragma unroll
  for (int nt = 0; nt < 8; ++nt)
#pragma unroll
    for (int r = 0; r < 4; ++r) acc[nt][r] = 0.f;

  const int s_cc = w * 8 + (lane >> 3);
  const int s_nb = (lane & 7) * 4;

  for (int c0 = 0; c0 < NC; c0 += 32) {
    __syncthreads();
    {
      const float* xsrc = x + ((size_t)(b * NC + c0 + s_cc)) * NN + n0 + s_nb;
#pragma unroll
      for (int it = 0; it < 4; ++it) {
        const float4 f = *(const float4*)(xsrc + it * 32);
        const int n = s_nb + it * 32;
        Xs[(n + 0) * LDX + s_cc] = f2bf(f.x);
        Xs[(n + 1) * LDX + s_cc] = f2bf(f.y);
        Xs[(n + 2) * LDX + s_cc] = f2bf(f.z);
        Xs[(n + 3) * LDX + s_cc] = f2bf(f.w);
      }
    }
    __syncthreads();

    const short8 ah = *(const short8*)&Ws[0][(w * 16 + c16) * LDW + c0 + g16 * 8];
    const short8 al = *(const short8*)&Ws[1][(w * 16 + c16) * LDW + c0 + g16 * 8];
#pragma unroll
    for (int nt = 0; nt < 8; ++nt) {
      const short8 bf = *(const short8*)&Xs[(nt * 16 + c16) * LDX + g16 * 8];
      acc[nt] = __builtin_amdgcn_mfma_f32_16x16x32_bf16(ah, bf, acc[nt], 0, 0, 0);
      acc[nt] = __builtin_amdgcn_mfma_f32_16x16x32_bf16(al, bf, acc[nt], 0, 0, 0);
    }
  }

  if (blockIdx.y == 0) {
    float bb[4];
#pragma unroll
    for (int r = 0; r < 4; ++r) {
      const int o = w * 16 + g16 * 4 + r;
      bb[r] = (o < 32) ? bq[o] * LOG2E : bk[o - 32];
    }
#pragma unroll
    for (int nt = 0; nt < 8; ++nt) {
      union { ushort u[4]; uint2 v; } pk;
#pragma unroll
      for (int r = 0; r < 4; ++r) pk.u[r] = f2bf(acc[nt][r] + bb[r]);
      const int n = n0 + nt * 16 + c16;
      *(uint2*)(qk + ((size_t)(b * NN + n)) * 64 + w * 16 + g16 * 4) = pk.v;
    }
  } else {
    const int ch0 = o0 - 64;
    float bb[4];
#pragma unroll
    for (int r = 0; r < 4; ++r) bb[r] = bv[ch0 + w * 16 + g16 * 4 + r];
    __syncthreads();
    ushort* Os = &Ws[0][0];
#pragma unroll
    for (int nt = 0; nt < 8; ++nt) {
#pragma unroll
      for (int r = 0; r < 4; ++r)
        Os[(w * 16 + g16 * 4 + r) * LDO + nt * 16 + c16] =
            f2bf(acc[nt][r] + bb[r]);
    }
    __syncthreads();
    const int chl = t >> 2;
    const int nb  = (t & 3) * 32;
    ushort* dst = vt + ((size_t)(b * NC + ch0 + chl)) * NN + n0 + nb;
#pragma unroll
    for (int k = 0; k < 4; ++k)
      *(uint4*)(dst + k * 8) = *(const uint4*)&Os[chl * LDO + nb + k * 8];
  }
}

// ---------------------------------------------------------------------------
// Flash attention — best measured configuration (R18/R22, attn ~145 us).
// 12-wave producer/consumer, 256 blocks x 768 threads, 3 waves/SIMD
// (1 S + 2 PV). ONE barrier per interval; P dbuf swizzled (128 KB).
//  Waves 0-3  (S): rows w*32..+32, kf[8] two half-chunk passes, swapped
//    mfma16(K,Q), exp2 (Q pre-scaled by log2e), packed b64 P writes.
//  Waves 4-11 (PV): 32 ch x 128 rows (OA[4] = 64 AGPR), 2-slot V rotation
//    refilled 2 steps ahead, 64 mfma32/chunk.
// Frame: VGPR 84 + AGPR 64 = 148 <= 170 cap -> no spill (validated).
// ---------------------------------------------------------------------------
__global__ __launch_bounds__(768, 3)
void attn_kernel(const ushort* __restrict__ qk, const ushort* __restrict__ vt,
                 const float* __restrict__ x, const float* __restrict__ gamma,
                 float* __restrict__ out) {
  __shared__ __align__(16) ushort P[2][128 * 256];   // 128 KB, swizzled
  __shared__ __align__(16) float lL[128];

  const int lin  = blockIdx.x;
  const int b    = lin & 7;              // XCD swizzle: batch per XCD L2
  const int i0   = (lin >> 3) * 128;
  const int t    = threadIdx.x;
  const int w    = t >> 6;               // 0..11
  const int lane = t & 63;
  const int g16  = lane >> 4;
  const int c16  = lane & 15;
  const int l5   = lane >> 5;
  const int c32  = lane & 31;

  const f32x4 zero = {0.f, 0.f, 0.f, 0.f};
  const bool isS = (w < 4);

  // ---- S state (waves 0-3): 32 q-rows each ----
  const int prow0 = w * 32 + c16;
  const int prow1 = prow0 + 16;
  short8 qf0, qf1;
  short8 kf[8];
  float lp0 = 0.f, lp1 = 0.f;
  const ushort* kbase = qk + ((size_t)b * NN) * 64 + 32 + g16 * 8;
  if (isS) {
    qf0 = *(const short8*)(qk + ((size_t)(b * NN + i0 + prow0)) * 64 + g16 * 8);
    qf1 = *(const short8*)(qk + ((size_t)(b * NN + i0 + prow1)) * 64 + g16 * 8);
  }

  // ---- PV state (waves 4-11): 32 channels x 128 rows ----
  const int p = w - 4;                   // 0..7
  f32x16 OA[4];
  const ushort* vptr = nullptr;
  if (!isS) {
#pragma unroll
    for (int isub = 0; isub < 4; ++isub)
#pragma unroll
      for (int e = 0; e < 16; ++e) OA[isub][e] = 0.f;
    vptr = vt + ((size_t)(b * NC + p * 32 + c32)) * NN + l5 * 8;
  }

  for (int iv = 0; iv <= NCH; ++iv) {
    if (isS) {
      if (iv < NCH) {
        ushort* Pb = P[iv & 1];
        const ushort* kch = kbase + (size_t)iv * 256 * 64;
#pragma unroll
        for (int h = 0; h < 2; ++h) {
#pragma unroll
          for (int jt = 0; jt < 8; ++jt)
            kf[jt] = *(const short8*)(
                kch + (size_t)(h * 128 + jt * 16 + c16) * 64);
#pragma unroll
          for (int jt = 0; jt < 8; ++jt) {
            const f32x4 s0 = __builtin_amdgcn_mfma_f32_16x16x32_bf16(
                kf[jt], qf0, zero, 0, 0, 0);
            const f32x4 s1 = __builtin_amdgcn_mfma_f32_16x16x32_bf16(
                kf[jt], qf1, zero, 0, 0, 0);
            union { ushort u[4]; uint2 v; } pk0, pk1;
#pragma unroll
            for (int r = 0; r < 4; ++r) {
              const float e0 = exp2f(s0[r]);
              const float e1 = exp2f(s1[r]);
              lp0 += e0; lp1 += e1;
              pk0.u[r] = f2bf(e0); pk1.u[r] = f2bf(e1);
            }
            const int col = h * 128 + jt * 16 + g16 * 4;
            *(uint2*)&Pb[PIDX(prow0, col)] = pk0.v;
            *(uint2*)&Pb[PIDX(prow1, col)] = pk1.v;
          }
        }
      } else {
        lp0 += __shfl_xor(lp0, 16); lp0 += __shfl_xor(lp0, 32);
        lp1 += __shfl_xor(lp1, 16); lp1 += __shfl_xor(lp1, 32);
        if (g16 == 0) { lL[prow0] = lp0; lL[prow1] = lp1; }
      }
    } else if (iv >= 1) {
      const int ch = iv - 1;
      const ushort* Pb = P[ch & 1];
      const int j0 = ch * 256;
      // 2-slot V rotation, refilled 2 steps ahead (within-chunk only)
      short8 vf[2];
      vf[0] = *(const short8*)(vptr + j0);
      vf[1] = *(const short8*)(vptr + j0 + 16);
      __builtin_amdgcn_s_setprio(1);
#pragma unroll
      for (int ji = 0; ji < 16; ++ji) {
        const short8 v0 = vf[ji & 1];
        if (ji < 14)
          vf[ji & 1] = *(const short8*)(vptr + j0 + (ji + 2) * 16);
        const int jo = ji * 16;
#pragma unroll
        for (int isub = 0; isub < 4; ++isub) {
          const short8 pa =
              *(const short8*)&Pb[PIDX(isub * 32 + c32, jo + l5 * 8)];
          OA[isub] = __builtin_amdgcn_mfma_f32_32x32x16_bf16(
              pa, v0, OA[isub], 0, 0, 0);
        }
      }
      __builtin_amdgcn_s_setprio(0);
    }
    __syncthreads();
  }

  // ---- epilogue: PV waves write out = gamma*O/l + x ----
  if (!isS) {
    const float g = gamma[0];
#pragma unroll
    for (int isub = 0; isub < 4; ++isub) {
#pragma unroll
      for (int q = 0; q < 4; ++q) {
        const int r0 = isub * 32 + q * 8 + l5 * 4;   // D row: (reg&3)+8q+4*l5
        const f32x4 li = *(const f32x4*)&lL[r0];
        f32x4 gi;
#pragma unroll
        for (int r = 0; r < 4; ++r) gi[r] = g / li[r];
        const int c = p * 32 + c32;
        const size_t base = ((size_t)(b * NC + c)) * NN + i0 + r0;
        const f32x4 xv = *(const f32x4*)(x + base);
        f32x4 ov;
#pragma unroll
        for (int r = 0; r < 4; ++r) ov[r] = OA[isub][q * 4 + r] * gi[r] + xv[r];
        *(f32x4*)(out + base) = ov;
      }
    }
  }
}

extern "C" void kernel_launch(void* const* d_in, const int* in_sizes, int n_in,
                              void* d_out, int out_size, void* d_ws, size_t ws_size,
                              hipStream_t stream) {
  const float* x  = (const float*)d_in[0];
  const float* wq = (const float*)d_in[1];
  const float* bq = (const float*)d_in[2];
  const float* wk = (const float*)d_in[3];
  const float* bk = (const float*)d_in[4];
  const float* wv = (const float*)d_in[5];
  const float* bv = (const float*)d_in[6];
  const float* gm = (const float*)d_in[7];
  float* outp = (float*)d_out;

  ushort* qkw = (ushort*)d_ws;                       // [B][N][64]  bf16, 4 MB
  ushort* vtw = qkw + (size_t)NB * NN * 64;          // [B][C][N]   bf16, 16 MB

  proj_kernel<<<dim3(NN / 128, 5, NB), 256, 0, stream>>>(
      x, wq, bq, wk, bk, wv, bv, qkw, vtw);
  attn_kernel<<<dim3((NN / 128) * NB), 768, 0, stream>>>(qkw, vtw, x, gm, outp);
}